// Round 1
// baseline (4162.568 us; speedup 1.0000x reference)
//
#include <hip/hip_runtime.h>
#include <hip/hip_bf16.h>
#include <cstddef>
#include <cstdint>

// GraphSAGE 2-layer forward for MI355X (gfx950).
// Layer l: out = h_self @ W_self + mean_neigh @ W_neigh + b  (+ReLU after layer 0)
//
// Strategy:
//  - aggregate: 1 wave (64 lanes) per edge; float4/lane covers the 256-f32 row;
//    unsafeAtomicAdd (HW global_atomic_add_f32) into sums[dst]; lane0 counts deg.
//  - mean: in-place sums *= 1/max(deg,1).
//  - gemm: fp32 register-blocked tiled GEMM, BM=64, BK=32, K=512 (self||neigh
//    concatenated), 256 threads, 8x8 (layer1) / 4x8 (layer2) per thread.
//    Layer-1 A_self is gathered via input_nodes on the fly.

#define HID 256

// ---------------- aggregation ----------------
template<bool GATHER>
__global__ __launch_bounds__(256) void sage_aggregate(
    const float* __restrict__ table,      // embed_table (GATHER) or h1
    const int* __restrict__ node_idx,     // input_nodes (GATHER) or unused
    const int* __restrict__ src,
    const int* __restrict__ dst,
    float* __restrict__ sums,             // [n_dst][256], pre-zeroed
    float* __restrict__ deg,              // [n_dst], pre-zeroed
    int E)
{
    int e = (int)((blockIdx.x * 256 + threadIdx.x) >> 6);
    int lane = threadIdx.x & 63;
    if (e >= E) return;
    int s = src[e];
    int d = dst[e];
    size_t row = GATHER ? (size_t)node_idx[s] : (size_t)s;
    float4 v = *(const float4*)(table + row * HID + lane * 4);
    float* out = sums + (size_t)d * HID + lane * 4;
    unsafeAtomicAdd(out + 0, v.x);
    unsafeAtomicAdd(out + 1, v.y);
    unsafeAtomicAdd(out + 2, v.z);
    unsafeAtomicAdd(out + 3, v.w);
    if (lane == 0) unsafeAtomicAdd(deg + d, 1.0f);
}

// ---------------- mean (in place) ----------------
__global__ __launch_bounds__(256) void sage_mean(
    float* __restrict__ sums, const float* __restrict__ deg, int rows)
{
    int i = blockIdx.x * 256 + threadIdx.x;     // float4 index
    int total = rows * (HID / 4);
    if (i >= total) return;
    int r = i >> 6;                              // / (HID/4)
    float inv = 1.0f / fmaxf(deg[r], 1.0f);
    float4* p = (float4*)sums + i;
    float4 v = *p;
    v.x *= inv; v.y *= inv; v.z *= inv; v.w *= inv;
    *p = v;
}

// ---------------- fused SAGE GEMM ----------------
// C[M][BN] = [A_self | A_mean] (M x 512) @ [W_self ; W_neigh] (512 x BN) + b
template<int BN, int TM, bool RELU, bool GATHER>
__global__ __launch_bounds__(256) void sage_gemm(
    const float* __restrict__ Aself,     // embed_table (GATHER) or h1
    const int* __restrict__ idx,         // input_nodes (GATHER) or unused
    const float* __restrict__ Amean,     // [M][256] (already divided by deg)
    const float* __restrict__ Wself,     // [256][BN]
    const float* __restrict__ Wneigh,    // [256][BN]
    const float* __restrict__ bias,      // [BN]
    float* __restrict__ Out,             // [M][BN]
    int M)
{
    constexpr int BM = 64;
    constexpr int BK = 32;
    constexpr int TN = 8;
    constexpr int TCOLS = BN / TN;            // 32 (BN=256) or 16 (BN=128)

    __shared__ float As[BK][BM + 4];          // k-major, padded
    __shared__ float Ws[BK][BN];

    const int t = threadIdx.x;
    const int block_row = blockIdx.x * BM;
    const int tc = t % TCOLS;
    const int tr = t / TCOLS;
    const int r0 = tr * TM;
    const int c0 = tc * TN;

    float acc[TM][TN] = {};

    for (int k0 = 0; k0 < 2 * HID; k0 += BK) {
        const bool self = (k0 < HID);
        const int kb = self ? k0 : (k0 - HID);

        // stage A tile: BM x BK = 2048 floats = 512 float4, 2 per thread
        #pragma unroll
        for (int l = 0; l < 2; ++l) {
            int li = t + l * 256;             // float4 index 0..511
            int r = li >> 3;                  // row in tile
            int kq = (li & 7) * 4;            // k offset in chunk
            int grow = block_row + r;
            const float* srcp;
            if (self) {
                size_t nrow = GATHER ? (size_t)idx[grow] : (size_t)grow;
                srcp = Aself + nrow * HID + kb + kq;
            } else {
                srcp = Amean + (size_t)grow * HID + kb + kq;
            }
            float4 v = *(const float4*)srcp;
            As[kq + 0][r] = v.x;
            As[kq + 1][r] = v.y;
            As[kq + 2][r] = v.z;
            As[kq + 3][r] = v.w;
        }

        // stage W tile: BK x BN floats
        constexpr int WF4 = BK * BN / 4;
        #pragma unroll
        for (int l = 0; l < WF4 / 256; ++l) {
            int li = t + l * 256;
            int kk = li / (BN / 4);
            int jj = (li % (BN / 4)) * 4;
            const float* wsrc = self ? (Wself + (size_t)(kb + kk) * BN + jj)
                                     : (Wneigh + (size_t)(kb + kk) * BN + jj);
            *(float4*)&Ws[kk][jj] = *(const float4*)wsrc;
        }

        __syncthreads();

        #pragma unroll
        for (int k = 0; k < BK; ++k) {
            float a[TM], w[TN];
            #pragma unroll
            for (int i = 0; i < TM; i += 4)
                *(float4*)&a[i] = *(const float4*)&As[k][r0 + i];
            #pragma unroll
            for (int j = 0; j < TN; j += 4)
                *(float4*)&w[j] = *(const float4*)&Ws[k][c0 + j];
            #pragma unroll
            for (int i = 0; i < TM; ++i)
                #pragma unroll
                for (int j = 0; j < TN; ++j)
                    acc[i][j] += a[i] * w[j];
        }

        __syncthreads();
    }

    // epilogue
    #pragma unroll
    for (int i = 0; i < TM; ++i) {
        size_t grow = block_row + r0 + i;
        #pragma unroll
        for (int j = 0; j < TN; j += 4) {
            float4 v;
            v.x = acc[i][j + 0] + bias[c0 + j + 0];
            v.y = acc[i][j + 1] + bias[c0 + j + 1];
            v.z = acc[i][j + 2] + bias[c0 + j + 2];
            v.w = acc[i][j + 3] + bias[c0 + j + 3];
            if (RELU) {
                v.x = fmaxf(v.x, 0.0f);
                v.y = fmaxf(v.y, 0.0f);
                v.z = fmaxf(v.z, 0.0f);
                v.w = fmaxf(v.w, 0.0f);
            }
            *(float4*)&Out[grow * BN + c0 + j] = v;
        }
    }
}

extern "C" void kernel_launch(void* const* d_in, const int* in_sizes, int n_in,
                              void* d_out, int out_size, void* d_ws, size_t ws_size,
                              hipStream_t stream) {
    const int*   input_nodes = (const int*)d_in[0];
    const int*   src0        = (const int*)d_in[1];
    const int*   dst0        = (const int*)d_in[2];
    const int*   src1        = (const int*)d_in[3];
    const int*   dst1        = (const int*)d_in[4];
    // d_in[5], d_in[6]: n_dst0, n_dst1 scalars (device); values fixed by problem
    const float* embed       = (const float*)d_in[7];
    const float* W_self0     = (const float*)d_in[8];
    const float* W_neigh0    = (const float*)d_in[9];
    const float* b0          = (const float*)d_in[10];
    const float* W_self1     = (const float*)d_in[11];
    const float* W_neigh1    = (const float*)d_in[12];
    const float* b1          = (const float*)d_in[13];
    float*       out         = (float*)d_out;

    const int E0 = in_sizes[1];
    const int E1 = in_sizes[3];
    const int N1 = 65536;   // n_dst0
    const int N2 = 4096;    // n_dst1

    // workspace layout (bytes)
    char* ws = (char*)d_ws;
    float* sums0 = (float*)(ws);                                   // 64 MB
    float* sums1 = (float*)(ws + (size_t)N1 * HID * 4);            // 4 MB
    float* deg0  = (float*)(ws + (size_t)(N1 + N2) * HID * 4);     // 256 KB
    float* deg1  = (float*)(ws + (size_t)(N1 + N2) * HID * 4 + N1 * 4);
    float* h1    = (float*)(ws + (size_t)(N1 + N2) * HID * 4 + (N1 + N2) * 4);

    size_t zero_bytes = (size_t)(N1 + N2) * HID * 4 + (size_t)(N1 + N2) * 4;
    hipMemsetAsync(d_ws, 0, zero_bytes, stream);

    // ---- layer 0 ----
    sage_aggregate<true><<<(E0 + 3) / 4, 256, 0, stream>>>(
        embed, input_nodes, src0, dst0, sums0, deg0, E0);
    sage_mean<<<(N1 * (HID / 4) + 255) / 256, 256, 0, stream>>>(sums0, deg0, N1);
    sage_gemm<256, 8, true, true><<<N1 / 64, 256, 0, stream>>>(
        embed, input_nodes, sums0, W_self0, W_neigh0, b0, h1, N1);

    // ---- layer 1 ----
    sage_aggregate<false><<<(E1 + 3) / 4, 256, 0, stream>>>(
        h1, nullptr, src1, dst1, sums1, deg1, E1);
    sage_mean<<<(N2 * (HID / 4) + 255) / 256, 256, 0, stream>>>(sums1, deg1, N2);
    sage_gemm<128, 4, false, false><<<N2 / 64, 256, 0, stream>>>(
        h1, nullptr, sums1, W_self1, W_neigh1, b1, out, N2);
}

// Round 2
// 830.560 us; speedup vs baseline: 5.0118x; 5.0118x over previous
//
#include <hip/hip_runtime.h>
#include <hip/hip_bf16.h>
#include <cstddef>
#include <cstdint>

// GraphSAGE 2-layer forward for MI355X (gfx950).
//
// Round 2: replace per-edge float-atomic scatter (4.2 GB of L2->HBM write
// thrash) with CSR-by-dst build + wave-per-dst gather-mean.
//
// Pipeline per layer:
//   hist(dst) -> exclusive scan (1 block) -> scatter edge source-rows
//   (pre-resolved through input_nodes for layer 0) -> wave-per-dst
//   gather+mean -> fused GEMM  out = [self|mean] @ [Wself;Wneigh] + b (+ReLU).

#define HID 256

// ---------------- CSR build ----------------
__global__ __launch_bounds__(256) void edge_hist(
    const int* __restrict__ dst, int* __restrict__ cnt, int E)
{
    int i = blockIdx.x * 256 + threadIdx.x;
    if (i < E) atomicAdd(&cnt[dst[i]], 1);
}

// one block, 256 threads; n multiple of 256. work may alias cnt.
__global__ __launch_bounds__(256) void exclusive_scan_small(
    const int* __restrict__ cnt, int* __restrict__ offs,
    int* __restrict__ work, int n)
{
    __shared__ int part[256];
    __shared__ int excl[257];
    const int t = threadIdx.x;
    const int ch = n >> 8;
    const int base = t * ch;
    int s = 0;
    for (int i = 0; i < ch; ++i) s += cnt[base + i];
    part[t] = s;
    __syncthreads();
    if (t == 0) {
        int r = 0;
        for (int i = 0; i < 256; ++i) { excl[i] = r; r += part[i]; }
        excl[256] = r;
    }
    __syncthreads();
    int run = excl[t];
    for (int i = 0; i < ch; ++i) {
        int c = cnt[base + i];          // read before write: work may alias cnt
        offs[base + i] = run;
        work[base + i] = run;
        run += c;
    }
    if (t == 255) offs[n] = run;
}

template<bool RESOLVE>
__global__ __launch_bounds__(256) void edge_scatter(
    const int* __restrict__ src, const int* __restrict__ dst,
    const int* __restrict__ node_idx,
    int* __restrict__ cursor, int* __restrict__ edge_rows, int E)
{
    int i = blockIdx.x * 256 + threadIdx.x;
    if (i < E) {
        int d = dst[i];
        int pos = atomicAdd(&cursor[d], 1);
        int s = src[i];
        edge_rows[pos] = RESOLVE ? node_idx[s] : s;
    }
}

// ---------------- gather + mean: one wave per dst ----------------
__global__ __launch_bounds__(256) void sage_gather_mean(
    const float* __restrict__ table,       // [*][256]
    const int* __restrict__ offs,          // [n_dst+1]
    const int* __restrict__ edge_rows,     // row index per edge (CSR order)
    float* __restrict__ mean_out,          // [n_dst][256]
    int n_dst)
{
    int w = blockIdx.x * 4 + (threadIdx.x >> 6);
    int lane = threadIdx.x & 63;
    if (w >= n_dst) return;
    int beg = offs[w];
    int end = offs[w + 1];
    float4 acc = make_float4(0.f, 0.f, 0.f, 0.f);
    for (int e = beg; e < end; ++e) {
        int r = edge_rows[e];
        float4 v = *((const float4*)(table + (size_t)r * HID) + lane);
        acc.x += v.x; acc.y += v.y; acc.z += v.z; acc.w += v.w;
    }
    float inv = 1.0f / (float)max(end - beg, 1);
    acc.x *= inv; acc.y *= inv; acc.z *= inv; acc.w *= inv;
    *((float4*)(mean_out + (size_t)w * HID) + lane) = acc;
}

// ---------------- fused SAGE GEMM ----------------
// C[M][BN] = [A_self | A_mean] (M x 512) @ [W_self ; W_neigh] (512 x BN) + b
template<int BN, int TM, bool RELU, bool GATHER>
__global__ __launch_bounds__(256) void sage_gemm(
    const float* __restrict__ Aself,     // embed_table (GATHER) or h1
    const int* __restrict__ idx,         // input_nodes (GATHER) or unused
    const float* __restrict__ Amean,     // [M][256] (already divided by deg)
    const float* __restrict__ Wself,     // [256][BN]
    const float* __restrict__ Wneigh,    // [256][BN]
    const float* __restrict__ bias,      // [BN]
    float* __restrict__ Out,             // [M][BN]
    int M)
{
    constexpr int BM = 64;
    constexpr int BK = 32;
    constexpr int TN = 8;
    constexpr int TCOLS = BN / TN;            // 32 (BN=256) or 16 (BN=128)

    __shared__ float As[BK][BM + 4];          // k-major, padded
    __shared__ float Ws[BK][BN];

    const int t = threadIdx.x;
    const int block_row = blockIdx.x * BM;
    const int tc = t % TCOLS;
    const int tr = t / TCOLS;
    const int r0 = tr * TM;
    const int c0 = tc * TN;

    float acc[TM][TN] = {};

    for (int k0 = 0; k0 < 2 * HID; k0 += BK) {
        const bool self = (k0 < HID);
        const int kb = self ? k0 : (k0 - HID);

        // stage A tile: BM x BK = 2048 floats = 512 float4, 2 per thread
        #pragma unroll
        for (int l = 0; l < 2; ++l) {
            int li = t + l * 256;             // float4 index 0..511
            int r = li >> 3;                  // row in tile
            int kq = (li & 7) * 4;            // k offset in chunk
            int grow = block_row + r;
            const float* srcp;
            if (self) {
                size_t nrow = GATHER ? (size_t)idx[grow] : (size_t)grow;
                srcp = Aself + nrow * HID + kb + kq;
            } else {
                srcp = Amean + (size_t)grow * HID + kb + kq;
            }
            float4 v = *(const float4*)srcp;
            As[kq + 0][r] = v.x;
            As[kq + 1][r] = v.y;
            As[kq + 2][r] = v.z;
            As[kq + 3][r] = v.w;
        }

        // stage W tile: BK x BN floats
        constexpr int WF4 = BK * BN / 4;
        #pragma unroll
        for (int l = 0; l < WF4 / 256; ++l) {
            int li = t + l * 256;
            int kk = li / (BN / 4);
            int jj = (li % (BN / 4)) * 4;
            const float* wsrc = self ? (Wself + (size_t)(kb + kk) * BN + jj)
                                     : (Wneigh + (size_t)(kb + kk) * BN + jj);
            *(float4*)&Ws[kk][jj] = *(const float4*)wsrc;
        }

        __syncthreads();

        #pragma unroll
        for (int k = 0; k < BK; ++k) {
            float a[TM], w[TN];
            #pragma unroll
            for (int i = 0; i < TM; i += 4)
                *(float4*)&a[i] = *(const float4*)&As[k][r0 + i];
            #pragma unroll
            for (int j = 0; j < TN; j += 4)
                *(float4*)&w[j] = *(const float4*)&Ws[k][c0 + j];
            #pragma unroll
            for (int i = 0; i < TM; ++i)
                #pragma unroll
                for (int j = 0; j < TN; ++j)
                    acc[i][j] += a[i] * w[j];
        }

        __syncthreads();
    }

    // epilogue
    #pragma unroll
    for (int i = 0; i < TM; ++i) {
        size_t grow = block_row + r0 + i;
        #pragma unroll
        for (int j = 0; j < TN; j += 4) {
            float4 v;
            v.x = acc[i][j + 0] + bias[c0 + j + 0];
            v.y = acc[i][j + 1] + bias[c0 + j + 1];
            v.z = acc[i][j + 2] + bias[c0 + j + 2];
            v.w = acc[i][j + 3] + bias[c0 + j + 3];
            if (RELU) {
                v.x = fmaxf(v.x, 0.0f);
                v.y = fmaxf(v.y, 0.0f);
                v.z = fmaxf(v.z, 0.0f);
                v.w = fmaxf(v.w, 0.0f);
            }
            *(float4*)&Out[grow * BN + c0 + j] = v;
        }
    }
}

extern "C" void kernel_launch(void* const* d_in, const int* in_sizes, int n_in,
                              void* d_out, int out_size, void* d_ws, size_t ws_size,
                              hipStream_t stream) {
    const int*   input_nodes = (const int*)d_in[0];
    const int*   src0        = (const int*)d_in[1];
    const int*   dst0        = (const int*)d_in[2];
    const int*   src1        = (const int*)d_in[3];
    const int*   dst1        = (const int*)d_in[4];
    const float* embed       = (const float*)d_in[7];
    const float* W_self0     = (const float*)d_in[8];
    const float* W_neigh0    = (const float*)d_in[9];
    const float* b0          = (const float*)d_in[10];
    const float* W_self1     = (const float*)d_in[11];
    const float* W_neigh1    = (const float*)d_in[12];
    const float* b1          = (const float*)d_in[13];
    float*       out         = (float*)d_out;

    const int E0 = in_sizes[1];
    const int E1 = in_sizes[3];
    const int N1 = 65536;   // n_dst0
    const int N2 = 4096;    // n_dst1

    // -------- workspace layout (liveness-aliased, 138.4 MB total) --------
    // [0,   64M): mean0            (live: aggregate0 -> gemm0)
    //             CSR1 aliases here (live: after gemm0)
    // [64M, 128M): h1              (live: gemm0 -> end)
    //             cnt0/offs0 alias here (live: before gemm0)
    // [128M, 132M): edges0         (live: scatter0 -> aggregate0)
    //             mean1 aliases here (live: aggregate1 -> gemm1)
    char* ws = (char*)d_ws;
    float* mean0  = (float*)ws;
    float* h1     = (float*)(ws + (size_t)67108864);
    int*   edges0 = (int*)(ws + (size_t)134217728);
    float* mean1  = (float*)edges0;

    int* cnt0  = (int*)h1;              // 65536 ints; also scan-work + cursor
    int* offs0 = cnt0 + 65536;          // 65537 ints

    int* cnt1   = (int*)mean0;          // 4096 ints; also scan-work + cursor
    int* offs1  = cnt1 + 4096;          // 4097 ints
    int* edges1 = offs1 + 4097;         // 65536 ints

    // ================= layer 0 =================
    hipMemsetAsync(cnt0, 0, (size_t)N1 * 4, stream);
    edge_hist<<<(E0 + 255) / 256, 256, 0, stream>>>(dst0, cnt0, E0);
    exclusive_scan_small<<<1, 256, 0, stream>>>(cnt0, offs0, cnt0, N1);
    edge_scatter<true><<<(E0 + 255) / 256, 256, 0, stream>>>(
        src0, dst0, input_nodes, cnt0, edges0, E0);
    sage_gather_mean<<<N1 / 4, 256, 0, stream>>>(
        embed, offs0, edges0, mean0, N1);
    sage_gemm<256, 8, true, true><<<N1 / 64, 256, 0, stream>>>(
        embed, input_nodes, mean0, W_self0, W_neigh0, b0, h1, N1);

    // ================= layer 1 =================
    hipMemsetAsync(cnt1, 0, (size_t)N2 * 4, stream);
    edge_hist<<<(E1 + 255) / 256, 256, 0, stream>>>(dst1, cnt1, E1);
    exclusive_scan_small<<<1, 256, 0, stream>>>(cnt1, offs1, cnt1, N2);
    edge_scatter<false><<<(E1 + 255) / 256, 256, 0, stream>>>(
        src1, dst1, nullptr, cnt1, edges1, E1);
    sage_gather_mean<<<N2 / 4, 256, 0, stream>>>(
        h1, offs1, edges1, mean1, N2);
    sage_gemm<128, 4, false, false><<<N2 / 64, 256, 0, stream>>>(
        h1, nullptr, mean1, W_self1, W_neigh1, b1, out, N2);
}

// Round 3
// 631.986 us; speedup vs baseline: 6.5865x; 1.3142x over previous
//
#include <hip/hip_runtime.h>
#include <hip/hip_bf16.h>
#include <cstddef>
#include <cstdint>

// GraphSAGE 2-layer forward for MI355X (gfx950).
//
// Round 3: bf16-MFMA GEMMs (16x16x32, f32 accum). W pre-transposed to
// WT[n][512] bf16 (self||neigh along k). A staged f32->bf16 into
// XOR-swizzled LDS. CSR gather-mean pipeline unchanged from round 2.

#define HID 256

using f32x4  = __attribute__((ext_vector_type(4))) float;
using bf16x8 = __attribute__((ext_vector_type(8))) short;

static __device__ __forceinline__ ushort f2bf(float f) {
    union { float f; unsigned u; } v; v.f = f;
    unsigned r = v.u + 0x7FFF + ((v.u >> 16) & 1);   // RNE
    return (ushort)(r >> 16);
}

// ---------------- CSR build ----------------
__global__ __launch_bounds__(256) void edge_hist(
    const int* __restrict__ dst, int* __restrict__ cnt, int E)
{
    int i = blockIdx.x * 256 + threadIdx.x;
    if (i < E) atomicAdd(&cnt[dst[i]], 1);
}

// one block, 256 threads; n multiple of 256. work may alias cnt.
__global__ __launch_bounds__(256) void exclusive_scan_small(
    const int* __restrict__ cnt, int* __restrict__ offs,
    int* __restrict__ work, int n)
{
    __shared__ int part[256];
    __shared__ int excl[257];
    const int t = threadIdx.x;
    const int ch = n >> 8;
    const int base = t * ch;
    int s = 0;
    for (int i = 0; i < ch; ++i) s += cnt[base + i];
    part[t] = s;
    __syncthreads();
    if (t == 0) {
        int r = 0;
        for (int i = 0; i < 256; ++i) { excl[i] = r; r += part[i]; }
        excl[256] = r;
    }
    __syncthreads();
    int run = excl[t];
    for (int i = 0; i < ch; ++i) {
        int c = cnt[base + i];
        offs[base + i] = run;
        work[base + i] = run;
        run += c;
    }
    if (t == 255) offs[n] = run;
}

template<bool RESOLVE>
__global__ __launch_bounds__(256) void edge_scatter(
    const int* __restrict__ src, const int* __restrict__ dst,
    const int* __restrict__ node_idx,
    int* __restrict__ cursor, int* __restrict__ edge_rows, int E)
{
    int i = blockIdx.x * 256 + threadIdx.x;
    if (i < E) {
        int d = dst[i];
        int pos = atomicAdd(&cursor[d], 1);
        int s = src[i];
        edge_rows[pos] = RESOLVE ? node_idx[s] : s;
    }
}

// ---------------- gather + mean: one wave per dst ----------------
__global__ __launch_bounds__(256) void sage_gather_mean(
    const float* __restrict__ table,       // [*][256]
    const int* __restrict__ offs,          // [n_dst+1]
    const int* __restrict__ edge_rows,     // row index per edge (CSR order)
    float* __restrict__ mean_out,          // [n_dst][256]
    int n_dst)
{
    int w = blockIdx.x * 4 + (threadIdx.x >> 6);
    int lane = threadIdx.x & 63;
    if (w >= n_dst) return;
    int beg = offs[w];
    int end = offs[w + 1];
    float4 acc = make_float4(0.f, 0.f, 0.f, 0.f);
    for (int e = beg; e < end; ++e) {
        int r = edge_rows[e];
        float4 v = *((const float4*)(table + (size_t)r * HID) + lane);
        acc.x += v.x; acc.y += v.y; acc.z += v.z; acc.w += v.w;
    }
    float inv = 1.0f / (float)max(end - beg, 1);
    acc.x *= inv; acc.y *= inv; acc.z *= inv; acc.w *= inv;
    *((float4*)(mean_out + (size_t)w * HID) + lane) = acc;
}

// ---------------- W pre-transpose + bf16 convert ----------------
// WT[n][k], k in [0,512): k<256 -> W_self[k][n], else W_neigh[k-256][n]
__global__ __launch_bounds__(256) void build_wt(
    const float* __restrict__ Wself, const float* __restrict__ Wneigh,
    ushort* __restrict__ WT, int N)
{
    int i = blockIdx.x * 256 + threadIdx.x;
    if (i >= N * 512) return;
    int n = i >> 9;
    int k = i & 511;
    float v = (k < HID) ? Wself[(size_t)k * N + n]
                        : Wneigh[(size_t)(k - HID) * N + n];
    WT[i] = f2bf(v);
}

// ---------------- bf16 MFMA fused SAGE GEMM ----------------
// Out[M][N_total] = [A_self | A_mean] (M x 512) @ WT^T + bias  (+ReLU)
// Tile 128x64, BK=64, 4 waves (2x2), each wave 64x32 = 4x2 16x16 frags.
template<bool RELU, bool GATHER>
__global__ __launch_bounds__(256) void sage_gemm_mfma(
    const float* __restrict__ Aself,     // embed_table (GATHER) or h1
    const int* __restrict__ idx,         // input_nodes (GATHER) or unused
    const float* __restrict__ Amean,     // [M][256] f32
    const ushort* __restrict__ WT,       // [N_total][512] bf16
    const float* __restrict__ bias,      // [N_total]
    float* __restrict__ Out,             // [M][N_total]
    int N_total)
{
    constexpr int BM = 128, BN = 64, BK = 64;
    __shared__ ushort As[BM * BK];       // [row][k], XOR-swizzled
    __shared__ ushort Bs[BN * BK];       // [col][k], XOR-swizzled

    const int t = threadIdx.x;
    const int brow = blockIdx.x * BM;
    const int bcol = blockIdx.y * BN;
    const int w = t >> 6, l = t & 63;
    const int wr = (w >> 1) * 64;        // wave row offset
    const int wc = (w & 1) * 32;         // wave col offset
    const int l15 = l & 15, l4 = l >> 4;

    f32x4 acc[4][2] = {};

    for (int k0 = 0; k0 < 2 * HID; k0 += BK) {
        const bool self = (k0 < HID);
        // ---- stage A: 128x64 f32 -> bf16 LDS ----
        #pragma unroll
        for (int i = 0; i < 8; ++i) {
            int li = t + i * 256;            // 0..2047 (float4 granules)
            int r  = li >> 4;                // row 0..127
            int k4 = (li & 15) << 2;         // k 0..60 step 4
            const float* sp;
            if (self) {
                size_t rg = GATHER ? (size_t)idx[brow + r] : (size_t)(brow + r);
                sp = Aself + rg * HID + k0 + k4;
            } else {
                sp = Amean + (size_t)(brow + r) * HID + (k0 - HID) + k4;
            }
            f32x4 v = *(const f32x4*)sp;
            ushort4 h;
            h.x = f2bf(v.x); h.y = f2bf(v.y); h.z = f2bf(v.z); h.w = f2bf(v.w);
            int di = (r * BK + k4) ^ ((r & 7) << 3);
            *(ushort4*)&As[di] = h;
        }
        // ---- stage B: 64x64 bf16 from WT ----
        #pragma unroll
        for (int i = 0; i < 4; ++i) {
            int li = t + i * 256;            // 0..1023 (ushort4 granules)
            int n  = li >> 4;                // col 0..63
            int k4 = (li & 15) << 2;
            ushort4 h = *(const ushort4*)(WT + (size_t)(bcol + n) * 512 + k0 + k4);
            int di = (n * BK + k4) ^ ((n & 7) << 3);
            *(ushort4*)&Bs[di] = h;
        }
        __syncthreads();

        // ---- MFMA: 2 kk-halves x 4m x 2n ----
        #pragma unroll
        for (int kk = 0; kk < 2; ++kk) {
            int koff = kk * 32 + l4 * 8;
            bf16x8 a[4], b[2];
            #pragma unroll
            for (int m = 0; m < 4; ++m) {
                int r = wr + m * 16 + l15;
                a[m] = *(const bf16x8*)&As[(r * BK + koff) ^ ((r & 7) << 3)];
            }
            #pragma unroll
            for (int n = 0; n < 2; ++n) {
                int c = wc + n * 16 + l15;
                b[n] = *(const bf16x8*)&Bs[(c * BK + koff) ^ ((c & 7) << 3)];
            }
            #pragma unroll
            for (int m = 0; m < 4; ++m)
                #pragma unroll
                for (int n = 0; n < 2; ++n)
                    acc[m][n] = __builtin_amdgcn_mfma_f32_16x16x32_bf16(
                        a[m], b[n], acc[m][n], 0, 0, 0);
        }
        __syncthreads();
    }

    // ---- epilogue: D[(l>>4)*4+r][l&15] per frag ----
    #pragma unroll
    for (int m = 0; m < 4; ++m) {
        #pragma unroll
        for (int n = 0; n < 2; ++n) {
            int col = bcol + wc + n * 16 + l15;
            float bv = bias[col];
            #pragma unroll
            for (int r = 0; r < 4; ++r) {
                int row = brow + wr + m * 16 + l4 * 4 + r;
                float v = acc[m][n][r] + bv;
                if (RELU) v = fmaxf(v, 0.f);
                Out[(size_t)row * N_total + col] = v;
            }
        }
    }
}

extern "C" void kernel_launch(void* const* d_in, const int* in_sizes, int n_in,
                              void* d_out, int out_size, void* d_ws, size_t ws_size,
                              hipStream_t stream) {
    const int*   input_nodes = (const int*)d_in[0];
    const int*   src0        = (const int*)d_in[1];
    const int*   dst0        = (const int*)d_in[2];
    const int*   src1        = (const int*)d_in[3];
    const int*   dst1        = (const int*)d_in[4];
    const float* embed       = (const float*)d_in[7];
    const float* W_self0     = (const float*)d_in[8];
    const float* W_neigh0    = (const float*)d_in[9];
    const float* b0          = (const float*)d_in[10];
    const float* W_self1     = (const float*)d_in[11];
    const float* W_neigh1    = (const float*)d_in[12];
    const float* b1          = (const float*)d_in[13];
    float*       out         = (float*)d_out;

    const int E0 = in_sizes[1];
    const int E1 = in_sizes[3];
    const int N1 = 65536;   // n_dst0
    const int N2 = 4096;    // n_dst1

    // -------- workspace layout (liveness-aliased) --------
    // [0,   64M): mean0 (aggregate0->gemm0); CSR1 tables alias after gemm0
    // [64M, 128M): h1 (gemm0->end); cnt0/offs0 alias before gemm0
    // [128M,132M): edges0 (scatter0->gather_mean0); mean1 aliases after
    // [132M, ...): WT0 (256KB), WT1 (128KB)
    char* ws = (char*)d_ws;
    float* mean0  = (float*)ws;
    float* h1     = (float*)(ws + (size_t)67108864);
    int*   edges0 = (int*)(ws + (size_t)134217728);
    float* mean1  = (float*)edges0;
    ushort* WT0   = (ushort*)(ws + (size_t)138412032);
    ushort* WT1   = WT0 + 256 * 512;

    int* cnt0  = (int*)h1;              // 65536 ints; scan-work + cursor
    int* offs0 = cnt0 + 65536;          // 65537 ints

    int* cnt1   = (int*)mean0;          // 4096 ints
    int* offs1  = cnt1 + 4096;          // 4097 ints
    int* edges1 = offs1 + 4097;         // 65536 ints

    // -------- W pre-transpose (both layers, independent) --------
    build_wt<<<512, 256, 0, stream>>>(W_self0, W_neigh0, WT0, 256);
    build_wt<<<256, 256, 0, stream>>>(W_self1, W_neigh1, WT1, 128);

    // ================= layer 0 =================
    hipMemsetAsync(cnt0, 0, (size_t)N1 * 4, stream);
    edge_hist<<<(E0 + 255) / 256, 256, 0, stream>>>(dst0, cnt0, E0);
    exclusive_scan_small<<<1, 256, 0, stream>>>(cnt0, offs0, cnt0, N1);
    edge_scatter<true><<<(E0 + 255) / 256, 256, 0, stream>>>(
        src0, dst0, input_nodes, cnt0, edges0, E0);
    sage_gather_mean<<<N1 / 4, 256, 0, stream>>>(
        embed, offs0, edges0, mean0, N1);
    {
        dim3 grid(N1 / 128, 256 / 64);
        sage_gemm_mfma<true, true><<<grid, 256, 0, stream>>>(
            embed, input_nodes, mean0, WT0, b0, h1, 256);
    }

    // ================= layer 1 =================
    hipMemsetAsync(cnt1, 0, (size_t)N2 * 4, stream);
    edge_hist<<<(E1 + 255) / 256, 256, 0, stream>>>(dst1, cnt1, E1);
    exclusive_scan_small<<<1, 256, 0, stream>>>(cnt1, offs1, cnt1, N2);
    edge_scatter<false><<<(E1 + 255) / 256, 256, 0, stream>>>(
        src1, dst1, nullptr, cnt1, edges1, E1);
    sage_gather_mean<<<N2 / 4, 256, 0, stream>>>(
        h1, offs1, edges1, mean1, N2);
    {
        dim3 grid(N2 / 128, 128 / 64);
        sage_gemm_mfma<false, false><<<grid, 256, 0, stream>>>(
            h1, nullptr, mean1, WT1, b1, out, 128);
    }
}

// Round 4
// 409.660 us; speedup vs baseline: 10.1610x; 1.5427x over previous
//
#include <hip/hip_runtime.h>
#include <hip/hip_bf16.h>
#include <cstddef>
#include <cstdint>

// GraphSAGE 2-layer forward for MI355X (gfx950).
//
// Round 4:
//  - GEMM tiles BM=64 x BN=N_total (A staged exactly once; was re-staged 4x)
//  - bf16 intermediates (mean0/h1/mean1) - halves intermediate traffic
//  - gather_mean: 8-deep MLP via lane-parallel index prefetch + shfl broadcast
//  - 3-phase parallel scan (was single-block)

#define HID 256

using f32x4  = __attribute__((ext_vector_type(4))) float;
using bf16x8 = __attribute__((ext_vector_type(8))) short;
using u16x8  = __attribute__((ext_vector_type(8))) unsigned short;

static __device__ __forceinline__ ushort f2bf(float f) {
    union { float f; unsigned u; } v; v.f = f;
    unsigned r = v.u + 0x7FFF + ((v.u >> 16) & 1);   // RNE
    return (ushort)(r >> 16);
}
static __device__ __forceinline__ float bf2f(ushort h) {
    union { unsigned u; float f; } v; v.u = ((unsigned)h) << 16;
    return v.f;
}

// ---------------- CSR build ----------------
__global__ __launch_bounds__(256) void edge_hist(
    const int* __restrict__ dst, int* __restrict__ cnt, int E)
{
    int i = blockIdx.x * 256 + threadIdx.x;
    if (i < E) atomicAdd(&cnt[dst[i]], 1);
}

// per-256-chunk exclusive scan; totals[b] = chunk sum
__global__ __launch_bounds__(256) void scan_block(
    const int* __restrict__ cnt, int* __restrict__ offs, int* __restrict__ totals)
{
    __shared__ int sh[256];
    int t = threadIdx.x;
    int i = blockIdx.x * 256 + t;
    int v = cnt[i];
    sh[t] = v;
    __syncthreads();
    #pragma unroll
    for (int d = 1; d < 256; d <<= 1) {
        int x = (t >= d) ? sh[t - d] : 0;
        __syncthreads();
        sh[t] += x;
        __syncthreads();
    }
    offs[i] = sh[t] - v;                    // exclusive within chunk
    if (t == 255) totals[blockIdx.x] = sh[t];
}

// single block: in-place exclusive scan of totals[0..nb)
__global__ __launch_bounds__(256) void scan_totals(
    int* __restrict__ totals, int nb)
{
    __shared__ int sh[256];
    int t = threadIdx.x;
    int v = (t < nb) ? totals[t] : 0;
    sh[t] = v;
    __syncthreads();
    #pragma unroll
    for (int d = 1; d < 256; d <<= 1) {
        int x = (t >= d) ? sh[t - d] : 0;
        __syncthreads();
        sh[t] += x;
        __syncthreads();
    }
    if (t < nb) totals[t] = sh[t] - v;
}

// offs += chunk base; cursor = offs; offs[n] = E
__global__ __launch_bounds__(256) void scan_add(
    int* __restrict__ offs, const int* __restrict__ totals,
    int* __restrict__ cursor, int n, int E)
{
    int i = blockIdx.x * 256 + threadIdx.x;
    if (i < n) {
        int v = offs[i] + totals[i >> 8];
        offs[i] = v;
        cursor[i] = v;
    }
    if (i == 0) offs[n] = E;
}

template<bool RESOLVE>
__global__ __launch_bounds__(256) void edge_scatter(
    const int* __restrict__ src, const int* __restrict__ dst,
    const int* __restrict__ node_idx,
    int* __restrict__ cursor, int* __restrict__ edge_rows, int E)
{
    int i = blockIdx.x * 256 + threadIdx.x;
    if (i < E) {
        int d = dst[i];
        int pos = atomicAdd(&cursor[d], 1);
        int s = src[i];
        edge_rows[pos] = RESOLVE ? node_idx[s] : s;
    }
}

// ---------------- gather + mean: one wave per dst, 8-deep MLP ----------------
// SRC_F32: table rows are f32[256]; else bf16[256]. Output bf16[256].
template<bool SRC_F32>
__global__ __launch_bounds__(256) void sage_gather_mean(
    const void* __restrict__ table,
    const int* __restrict__ offs,
    const int* __restrict__ edge_rows,
    ushort* __restrict__ mean_out,
    int n_dst)
{
    int w = blockIdx.x * 4 + (threadIdx.x >> 6);
    int lane = threadIdx.x & 63;
    if (w >= n_dst) return;
    int beg = offs[w], end = offs[w + 1];
    float a0 = 0.f, a1 = 0.f, a2 = 0.f, a3 = 0.f;
    int e = beg;
    while (e < end) {
        int cnt = end - e; cnt = cnt > 8 ? 8 : cnt;
        int myrow = 0;
        if (lane < cnt) myrow = edge_rows[e + lane];
        f32x4  vf[8];
        ushort4 vh[8];
        #pragma unroll
        for (int j = 0; j < 8; ++j) {
            if (j < cnt) {                       // wave-uniform predicate
                int r = __shfl(myrow, j);
                if (SRC_F32)
                    vf[j] = *((const f32x4*)((const float*)table + (size_t)r * HID) + lane);
                else
                    vh[j] = *((const ushort4*)((const ushort*)table + (size_t)r * HID) + lane);
            }
        }
        #pragma unroll
        for (int j = 0; j < 8; ++j) {
            if (j < cnt) {
                if (SRC_F32) { a0 += vf[j].x; a1 += vf[j].y; a2 += vf[j].z; a3 += vf[j].w; }
                else { a0 += bf2f(vh[j].x); a1 += bf2f(vh[j].y); a2 += bf2f(vh[j].z); a3 += bf2f(vh[j].w); }
            }
        }
        e += cnt;
    }
    float inv = 1.0f / (float)max(end - beg, 1);
    ushort4 o;
    o.x = f2bf(a0 * inv); o.y = f2bf(a1 * inv);
    o.z = f2bf(a2 * inv); o.w = f2bf(a3 * inv);
    *((ushort4*)(mean_out + (size_t)w * HID) + lane) = o;
}

// ---------------- W pre-transpose + bf16 convert ----------------
// WT[n][k], k in [0,512): k<256 -> W_self[k][n], else W_neigh[k-256][n]
__global__ __launch_bounds__(256) void build_wt(
    const float* __restrict__ Wself, const float* __restrict__ Wneigh,
    ushort* __restrict__ WT, int N)
{
    int i = blockIdx.x * 256 + threadIdx.x;
    if (i >= N * 512) return;
    int n = i >> 9;
    int k = i & 511;
    float v = (k < HID) ? Wself[(size_t)k * N + n]
                        : Wneigh[(size_t)(k - HID) * N + n];
    WT[i] = f2bf(v);
}

// ---------------- bf16 MFMA fused SAGE GEMM ----------------
// Out[M][BN] = [A_self | A_mean] (M x 512) @ WT^T + bias  (+ReLU)
// BM=64, BN=N_total (A staged once), BK=64, 4 waves: 1x4 (BN=256) or 2x2 (BN=128).
template<int BN, bool RELU, bool GATHER, bool SELF_F32, bool OUT_BF16>
__global__ __launch_bounds__(256) void sage_gemm_mfma(
    const void* __restrict__ Aself,      // f32 embed (SELF_F32) or bf16 h1
    const int* __restrict__ idx,         // input_nodes (GATHER) or unused
    const ushort* __restrict__ Amean,    // [M][256] bf16
    const ushort* __restrict__ WT,       // [BN][512] bf16
    const float* __restrict__ bias,      // [BN]
    void* __restrict__ Out)              // [M][BN] bf16 or f32
{
    constexpr int BM = 64, BK = 64;
    constexpr int WN = BN / 64;          // waves along N (4 or 2)
    constexpr int WM = 4 / WN;           // waves along M (1 or 2)
    constexpr int M_FR = (BM / WM) / 16; // m-frags per wave (4 or 2)

    __shared__ __align__(16) ushort As[BM * BK];
    __shared__ __align__(16) ushort Bs[BN * BK];

    const int t = threadIdx.x;
    const int brow = blockIdx.x * BM;
    const int w = t >> 6, l = t & 63;
    const int wc = (w % WN) * 64;
    const int wr = (w / WN) * (BM / WM);
    const int l15 = l & 15, l4 = l >> 4;

    f32x4 acc[M_FR][4] = {};

    for (int k0 = 0; k0 < 2 * HID; k0 += BK) {
        const bool self = (k0 < HID);

        // ---- stage A (64 x 64) ----
        if (self && SELF_F32) {
            #pragma unroll
            for (int i = 0; i < 4; ++i) {
                int li = t + i * 256;            // 1024 f32x4 granules
                int r  = li >> 4;
                int k4 = (li & 15) << 2;
                size_t rg = GATHER ? (size_t)idx[brow + r] : (size_t)(brow + r);
                f32x4 v = *(const f32x4*)((const float*)Aself + rg * HID + k0 + k4);
                ushort4 h;
                h.x = f2bf(v.x); h.y = f2bf(v.y); h.z = f2bf(v.z); h.w = f2bf(v.w);
                *(ushort4*)&As[(r * BK + k4) ^ ((r & 7) << 3)] = h;
            }
        } else {
            #pragma unroll
            for (int i = 0; i < 2; ++i) {
                int li = t + i * 256;            // 512 u16x8 granules
                int r  = li >> 3;
                int k8 = (li & 7) << 3;
                const ushort* sp;
                if (self) {
                    size_t rg = GATHER ? (size_t)idx[brow + r] : (size_t)(brow + r);
                    sp = (const ushort*)Aself + rg * HID + k0 + k8;
                } else {
                    sp = Amean + (size_t)(brow + r) * HID + (k0 - HID) + k8;
                }
                *(u16x8*)&As[(r * BK + k8) ^ ((r & 7) << 3)] = *(const u16x8*)sp;
            }
        }

        // ---- stage B (BN x 64) ----
        #pragma unroll
        for (int i = 0; i < BN / 32; ++i) {
            int li = t + i * 256;                // BN*8 u16x8 granules
            int n  = li >> 3;
            int k8 = (li & 7) << 3;
            *(u16x8*)&Bs[(n * BK + k8) ^ ((n & 7) << 3)] =
                *(const u16x8*)(WT + (size_t)n * 512 + k0 + k8);
        }
        __syncthreads();

        // ---- MFMA ----
        #pragma unroll
        for (int kk = 0; kk < 2; ++kk) {
            int koff = kk * 32 + l4 * 8;
            bf16x8 a[M_FR], b[4];
            #pragma unroll
            for (int m = 0; m < M_FR; ++m) {
                int r = wr + m * 16 + l15;
                a[m] = *(const bf16x8*)&As[(r * BK + koff) ^ ((r & 7) << 3)];
            }
            #pragma unroll
            for (int n = 0; n < 4; ++n) {
                int c = wc + n * 16 + l15;
                b[n] = *(const bf16x8*)&Bs[(c * BK + koff) ^ ((c & 7) << 3)];
            }
            #pragma unroll
            for (int m = 0; m < M_FR; ++m)
                #pragma unroll
                for (int n = 0; n < 4; ++n)
                    acc[m][n] = __builtin_amdgcn_mfma_f32_16x16x32_bf16(
                        a[m], b[n], acc[m][n], 0, 0, 0);
        }
        __syncthreads();
    }

    // ---- epilogue: D[(l>>4)*4+r][l&15] per frag ----
    #pragma unroll
    for (int m = 0; m < M_FR; ++m) {
        #pragma unroll
        for (int n = 0; n < 4; ++n) {
            int col = wc + n * 16 + l15;
            float bv = bias[col];
            #pragma unroll
            for (int r = 0; r < 4; ++r) {
                int row = brow + wr + m * 16 + l4 * 4 + r;
                float v = acc[m][n][r] + bv;
                if (RELU) v = fmaxf(v, 0.f);
                if (OUT_BF16) ((ushort*)Out)[(size_t)row * BN + col] = f2bf(v);
                else          ((float*)Out)[(size_t)row * BN + col] = v;
            }
        }
    }
}

extern "C" void kernel_launch(void* const* d_in, const int* in_sizes, int n_in,
                              void* d_out, int out_size, void* d_ws, size_t ws_size,
                              hipStream_t stream) {
    const int*   input_nodes = (const int*)d_in[0];
    const int*   src0        = (const int*)d_in[1];
    const int*   dst0        = (const int*)d_in[2];
    const int*   src1        = (const int*)d_in[3];
    const int*   dst1        = (const int*)d_in[4];
    const float* embed       = (const float*)d_in[7];
    const float* W_self0     = (const float*)d_in[8];
    const float* W_neigh0    = (const float*)d_in[9];
    const float* b0          = (const float*)d_in[10];
    const float* W_self1     = (const float*)d_in[11];
    const float* W_neigh1    = (const float*)d_in[12];
    const float* b1          = (const float*)d_in[13];
    float*       out         = (float*)d_out;

    const int E0 = in_sizes[1];
    const int E1 = in_sizes[3];
    const int N1 = 65536;   // n_dst0
    const int N2 = 4096;    // n_dst1

    // -------- workspace layout (no aliasing; ~78 MB) --------
    char* ws = (char*)d_ws;
    ushort* mean0  = (ushort*)(ws + ((size_t)0  << 20));   // 32 MB bf16
    ushort* h1     = (ushort*)(ws + ((size_t)32 << 20));   // 32 MB bf16
    int*    edges0 = (int*)  (ws + ((size_t)64 << 20));    // 4 MB
    int*    edges1 = (int*)  (ws + ((size_t)68 << 20));    // 256 KB
    int*    cnt0   = (int*)  (ws + ((size_t)69 << 20));    // 256 KB (also cursor)
    int*    offs0  = (int*)  (ws + ((size_t)70 << 20));    // 256 KB + 4
    int*    cnt1   = (int*)  (ws + ((size_t)71 << 20));    // 16 KB (also cursor)
    int*    offs1  = (int*)  (ws + ((size_t)72 << 20));    // 16 KB + 4
    int*    tot0   = (int*)  (ws + ((size_t)73 << 20));    // 1 KB
    int*    tot1   = (int*)  (ws + ((size_t)73 << 20) + 4096);
    ushort* WT0    = (ushort*)(ws + ((size_t)74 << 20));   // 256 KB
    ushort* WT1    = (ushort*)(ws + ((size_t)75 << 20));   // 128 KB
    ushort* mean1  = (ushort*)(ws + ((size_t)76 << 20));   // 2 MB

    // -------- W pre-transpose --------
    build_wt<<<512, 256, 0, stream>>>(W_self0, W_neigh0, WT0, 256);
    build_wt<<<256, 256, 0, stream>>>(W_self1, W_neigh1, WT1, 128);

    // ================= layer 0 =================
    hipMemsetAsync(cnt0, 0, (size_t)N1 * 4, stream);
    edge_hist<<<(E0 + 255) / 256, 256, 0, stream>>>(dst0, cnt0, E0);
    scan_block<<<N1 / 256, 256, 0, stream>>>(cnt0, offs0, tot0);
    scan_totals<<<1, 256, 0, stream>>>(tot0, N1 / 256);
    scan_add<<<N1 / 256, 256, 0, stream>>>(offs0, tot0, cnt0, N1, E0);
    edge_scatter<true><<<(E0 + 255) / 256, 256, 0, stream>>>(
        src0, dst0, input_nodes, cnt0, edges0, E0);
    sage_gather_mean<true><<<N1 / 4, 256, 0, stream>>>(
        embed, offs0, edges0, mean0, N1);
    sage_gemm_mfma<256, true, true, true, true><<<N1 / 64, 256, 0, stream>>>(
        embed, input_nodes, mean0, WT0, b0, h1);

    // ================= layer 1 =================
    hipMemsetAsync(cnt1, 0, (size_t)N2 * 4, stream);
    edge_hist<<<(E1 + 255) / 256, 256, 0, stream>>>(dst1, cnt1, E1);
    scan_block<<<N2 / 256, 256, 0, stream>>>(cnt1, offs1, tot1);
    scan_totals<<<1, 256, 0, stream>>>(tot1, N2 / 256);
    scan_add<<<N2 / 256, 256, 0, stream>>>(offs1, tot1, cnt1, N2, E1);
    edge_scatter<false><<<(E1 + 255) / 256, 256, 0, stream>>>(
        src1, dst1, nullptr, cnt1, edges1, E1);
    sage_gather_mean<false><<<N2 / 4, 256, 0, stream>>>(
        h1, offs1, edges1, mean1, N2);
    sage_gemm_mfma<128, false, false, false, false><<<N2 / 64, 256, 0, stream>>>(
        h1, nullptr, mean1, WT1, b1, out);
}

// Round 5
// 340.026 us; speedup vs baseline: 12.2419x; 1.2048x over previous
//
#include <hip/hip_runtime.h>
#include <hip/hip_bf16.h>
#include <cstddef>
#include <cstdint>

// GraphSAGE 2-layer forward for MI355X (gfx950).
//
// Round 5:
//  - fused CSR build for BOTH layers (contiguous cnt01/offs01/edges01;
//    combined scan gives layer-1 absolute offsets for free): 12 -> 6 dispatches
//  - fused build_wt
//  - GEMM: T14 reg-staged prefetch (load k+1 before MFMA k, LDS-write after
//    barrier) to hide global latency under MFMA
// Total 11 dispatches (was 20).

#define HID 256
#define N1 65536
#define N2 4096

using f32x4  = __attribute__((ext_vector_type(4))) float;
using bf16x8 = __attribute__((ext_vector_type(8))) short;
using u16x8  = __attribute__((ext_vector_type(8))) unsigned short;

static __device__ __forceinline__ ushort f2bf(float f) {
    union { float f; unsigned u; } v; v.f = f;
    unsigned r = v.u + 0x7FFF + ((v.u >> 16) & 1);   // RNE
    return (ushort)(r >> 16);
}
static __device__ __forceinline__ float bf2f(ushort h) {
    union { unsigned u; float f; } v; v.u = ((unsigned)h) << 16;
    return v.f;
}

// ---------------- W pre-transpose (both layers) ----------------
// WT[n][k], k in [0,512): k<256 -> W_self[k][n], else W_neigh[k-256][n]
__global__ __launch_bounds__(256) void build_wt01(
    const float* __restrict__ Ws0, const float* __restrict__ Wn0,
    const float* __restrict__ Ws1, const float* __restrict__ Wn1,
    ushort* __restrict__ WT0, ushort* __restrict__ WT1)
{
    int i = blockIdx.x * 256 + threadIdx.x;
    if (i < 256 * 512) {
        int n = i >> 9, k = i & 511;
        float v = (k < HID) ? Ws0[(size_t)k * 256 + n] : Wn0[(size_t)(k - HID) * 256 + n];
        WT0[i] = f2bf(v);
    } else {
        int j = i - 256 * 512;
        int n = j >> 9, k = j & 511;
        float v = (k < HID) ? Ws1[(size_t)k * 128 + n] : Wn1[(size_t)(k - HID) * 128 + n];
        WT1[j] = f2bf(v);
    }
}

// ---------------- fused CSR build ----------------
__global__ __launch_bounds__(256) void edge_hist01(
    const int* __restrict__ dst0, const int* __restrict__ dst1,
    int* __restrict__ cnt01, int E0, int E1)
{
    int i = blockIdx.x * 256 + threadIdx.x;
    if (i < E0) atomicAdd(&cnt01[dst0[i]], 1);
    else if (i < E0 + E1) atomicAdd(&cnt01[N1 + dst1[i - E0]], 1);
}

// per-256-chunk exclusive scan; totals[b] = chunk sum
__global__ __launch_bounds__(256) void scan_block(
    const int* __restrict__ cnt, int* __restrict__ offs, int* __restrict__ totals)
{
    __shared__ int sh[256];
    int t = threadIdx.x;
    int i = blockIdx.x * 256 + t;
    int v = cnt[i];
    sh[t] = v;
    __syncthreads();
    #pragma unroll
    for (int d = 1; d < 256; d <<= 1) {
        int x = (t >= d) ? sh[t - d] : 0;
        __syncthreads();
        sh[t] += x;
        __syncthreads();
    }
    offs[i] = sh[t] - v;
    if (t == 255) totals[blockIdx.x] = sh[t];
}

// single block, 512 threads: in-place exclusive scan of totals[0..nb), nb<=512
__global__ __launch_bounds__(512) void scan_totals(
    int* __restrict__ totals, int nb)
{
    __shared__ int sh[512];
    int t = threadIdx.x;
    int v = (t < nb) ? totals[t] : 0;
    sh[t] = v;
    __syncthreads();
    #pragma unroll
    for (int d = 1; d < 512; d <<= 1) {
        int x = (t >= d) ? sh[t - d] : 0;
        __syncthreads();
        sh[t] += x;
        __syncthreads();
    }
    if (t < nb) totals[t] = sh[t] - v;
}

// offs += chunk base; cursor = offs; sentinel
__global__ __launch_bounds__(256) void scan_add(
    int* __restrict__ offs, const int* __restrict__ totals,
    int* __restrict__ cursor, int n, int total_edges)
{
    int i = blockIdx.x * 256 + threadIdx.x;
    if (i < n) {
        int v = offs[i] + totals[i >> 8];
        offs[i] = v;
        cursor[i] = v;
    }
    if (i == 0) offs[n] = total_edges;
}

__global__ __launch_bounds__(256) void edge_scatter01(
    const int* __restrict__ src0, const int* __restrict__ dst0,
    const int* __restrict__ src1, const int* __restrict__ dst1,
    const int* __restrict__ node_idx,
    int* __restrict__ cursor, int* __restrict__ edge_rows, int E0, int E1)
{
    int i = blockIdx.x * 256 + threadIdx.x;
    if (i < E0) {
        int pos = atomicAdd(&cursor[dst0[i]], 1);
        edge_rows[pos] = node_idx[src0[i]];
    } else if (i < E0 + E1) {
        int e = i - E0;
        int pos = atomicAdd(&cursor[N1 + dst1[e]], 1);
        edge_rows[pos] = src1[e];
    }
}

// ---------------- gather + mean: one wave per dst, 8-deep MLP ----------------
template<bool SRC_F32>
__global__ __launch_bounds__(256) void sage_gather_mean(
    const void* __restrict__ table,
    const int* __restrict__ offs,          // absolute positions
    const int* __restrict__ edge_rows,
    ushort* __restrict__ mean_out,
    int n_dst)
{
    int w = blockIdx.x * 4 + (threadIdx.x >> 6);
    int lane = threadIdx.x & 63;
    if (w >= n_dst) return;
    int beg = offs[w], end = offs[w + 1];
    float a0 = 0.f, a1 = 0.f, a2 = 0.f, a3 = 0.f;
    int e = beg;
    while (e < end) {
        int cnt = end - e; cnt = cnt > 8 ? 8 : cnt;
        int myrow = 0;
        if (lane < cnt) myrow = edge_rows[e + lane];
        f32x4  vf[8];
        ushort4 vh[8];
        #pragma unroll
        for (int j = 0; j < 8; ++j) {
            if (j < cnt) {
                int r = __shfl(myrow, j);
                if (SRC_F32)
                    vf[j] = *((const f32x4*)((const float*)table + (size_t)r * HID) + lane);
                else
                    vh[j] = *((const ushort4*)((const ushort*)table + (size_t)r * HID) + lane);
            }
        }
        #pragma unroll
        for (int j = 0; j < 8; ++j) {
            if (j < cnt) {
                if (SRC_F32) { a0 += vf[j].x; a1 += vf[j].y; a2 += vf[j].z; a3 += vf[j].w; }
                else { a0 += bf2f(vh[j].x); a1 += bf2f(vh[j].y); a2 += bf2f(vh[j].z); a3 += bf2f(vh[j].w); }
            }
        }
        e += cnt;
    }
    float inv = 1.0f / (float)max(end - beg, 1);
    ushort4 o;
    o.x = f2bf(a0 * inv); o.y = f2bf(a1 * inv);
    o.z = f2bf(a2 * inv); o.w = f2bf(a3 * inv);
    *((ushort4*)(mean_out + (size_t)w * HID) + lane) = o;
}

// ---------------- bf16 MFMA fused SAGE GEMM (T14 reg-prefetch) ----------------
// Out[M][BN] = [A_self | A_mean] (M x 512) @ WT^T + bias  (+ReLU)
// BM=64, BN=N_total, BK=64, 4 waves: 1x4 (BN=256) or 2x2 (BN=128).
template<int BN, bool RELU, bool GATHER, bool SELF_F32, bool OUT_BF16>
__global__ __launch_bounds__(256) void sage_gemm_mfma(
    const void* __restrict__ Aself,      // f32 embed (SELF_F32) or bf16 h1
    const int* __restrict__ idx,         // input_nodes (GATHER) or unused
    const ushort* __restrict__ Amean,    // [M][256] bf16
    const ushort* __restrict__ WT,       // [BN][512] bf16
    const float* __restrict__ bias,      // [BN]
    void* __restrict__ Out)              // [M][BN] bf16 or f32
{
    constexpr int BM = 64, BK = 64;
    constexpr int WN = BN / 64;
    constexpr int WM = 4 / WN;
    constexpr int M_FR = (BM / WM) / 16;

    __shared__ __align__(16) ushort As[BM * BK];
    __shared__ __align__(16) ushort Bs[BN * BK];

    const int t = threadIdx.x;
    const int brow = blockIdx.x * BM;
    const int w = t >> 6, l = t & 63;
    const int wc = (w % WN) * 64;
    const int wr = (w / WN) * (BM / WM);
    const int l15 = l & 15, l4 = l >> 4;

    f32x4 acc[M_FR][4] = {};
    f32x4 af[4];
    u16x8 ah[2];
    u16x8 bh[BN / 32];

    auto load_step = [&](int k0) {
        if (SELF_F32 && k0 < HID) {
            #pragma unroll
            for (int i = 0; i < 4; ++i) {
                int li = t + i * 256; int r = li >> 4; int k4 = (li & 15) << 2;
                size_t rg = GATHER ? (size_t)idx[brow + r] : (size_t)(brow + r);
                af[i] = *(const f32x4*)((const float*)Aself + rg * HID + k0 + k4);
            }
        } else {
            #pragma unroll
            for (int i = 0; i < 2; ++i) {
                int li = t + i * 256; int r = li >> 3; int k8 = (li & 7) << 3;
                const ushort* sp;
                if (k0 < HID) {
                    size_t rg = GATHER ? (size_t)idx[brow + r] : (size_t)(brow + r);
                    sp = (const ushort*)Aself + rg * HID + k0 + k8;
                } else {
                    sp = Amean + (size_t)(brow + r) * HID + (k0 - HID) + k8;
                }
                ah[i] = *(const u16x8*)sp;
            }
        }
        #pragma unroll
        for (int i = 0; i < BN / 32; ++i) {
            int li = t + i * 256; int n = li >> 3; int k8 = (li & 7) << 3;
            bh[i] = *(const u16x8*)(WT + (size_t)n * 512 + k0 + k8);
        }
    };

    auto store_step = [&](int k0) {
        if (SELF_F32 && k0 < HID) {
            #pragma unroll
            for (int i = 0; i < 4; ++i) {
                int li = t + i * 256; int r = li >> 4; int k4 = (li & 15) << 2;
                ushort4 h;
                h.x = f2bf(af[i].x); h.y = f2bf(af[i].y);
                h.z = f2bf(af[i].z); h.w = f2bf(af[i].w);
                *(ushort4*)&As[(r * BK + k4) ^ ((r & 7) << 3)] = h;
            }
        } else {
            #pragma unroll
            for (int i = 0; i < 2; ++i) {
                int li = t + i * 256; int r = li >> 3; int k8 = (li & 7) << 3;
                *(u16x8*)&As[(r * BK + k8) ^ ((r & 7) << 3)] = ah[i];
            }
        }
        #pragma unroll
        for (int i = 0; i < BN / 32; ++i) {
            int li = t + i * 256; int n = li >> 3; int k8 = (li & 7) << 3;
            *(u16x8*)&Bs[(n * BK + k8) ^ ((n & 7) << 3)] = bh[i];
        }
    };

    load_step(0);
    store_step(0);
    __syncthreads();

    for (int k0 = 0; k0 < 2 * HID; k0 += BK) {
        int kn = k0 + BK;
        if (kn < 2 * HID) load_step(kn);       // prefetch to regs (overlaps MFMA)

        #pragma unroll
        for (int kk = 0; kk < 2; ++kk) {
            int koff = kk * 32 + l4 * 8;
            bf16x8 a[M_FR], b[4];
            #pragma unroll
            for (int m = 0; m < M_FR; ++m) {
                int r = wr + m * 16 + l15;
                a[m] = *(const bf16x8*)&As[(r * BK + koff) ^ ((r & 7) << 3)];
            }
            #pragma unroll
            for (int n = 0; n < 4; ++n) {
                int c = wc + n * 16 + l15;
                b[n] = *(const bf16x8*)&Bs[(c * BK + koff) ^ ((c & 7) << 3)];
            }
            #pragma unroll
            for (int m = 0; m < M_FR; ++m)
                #pragma unroll
                for (int n = 0; n < 4; ++n)
                    acc[m][n] = __builtin_amdgcn_mfma_f32_16x16x32_bf16(
                        a[m], b[n], acc[m][n], 0, 0, 0);
        }
        __syncthreads();
        if (kn < 2 * HID) store_step(kn);
        __syncthreads();
    }

    // ---- epilogue: D[(l>>4)*4+r][l&15] per frag ----
    #pragma unroll
    for (int m = 0; m < M_FR; ++m) {
        #pragma unroll
        for (int n = 0; n < 4; ++n) {
            int col = wc + n * 16 + l15;
            float bv = bias[col];
            #pragma unroll
            for (int r = 0; r < 4; ++r) {
                int row = brow + wr + m * 16 + l4 * 4 + r;
                float v = acc[m][n][r] + bv;
                if (RELU) v = fmaxf(v, 0.f);
                if (OUT_BF16) ((ushort*)Out)[(size_t)row * BN + col] = f2bf(v);
                else          ((float*)Out)[(size_t)row * BN + col] = v;
            }
        }
    }
}

extern "C" void kernel_launch(void* const* d_in, const int* in_sizes, int n_in,
                              void* d_out, int out_size, void* d_ws, size_t ws_size,
                              hipStream_t stream) {
    const int*   input_nodes = (const int*)d_in[0];
    const int*   src0        = (const int*)d_in[1];
    const int*   dst0        = (const int*)d_in[2];
    const int*   src1        = (const int*)d_in[3];
    const int*   dst1        = (const int*)d_in[4];
    const float* embed       = (const float*)d_in[7];
    const float* W_self0     = (const float*)d_in[8];
    const float* W_neigh0    = (const float*)d_in[9];
    const float* b0          = (const float*)d_in[10];
    const float* W_self1     = (const float*)d_in[11];
    const float* W_neigh1    = (const float*)d_in[12];
    const float* b1          = (const float*)d_in[13];
    float*       out         = (float*)d_out;

    const int E0 = in_sizes[1];          // 1048576
    const int E1 = in_sizes[3];          // 65536
    const int NC = N1 + N2;              // 69632 combined counters (272*256)

    // -------- workspace layout --------
    char* ws = (char*)d_ws;
    ushort* mean0   = (ushort*)(ws + ((size_t)0  << 20));  // 32 MB bf16
    ushort* h1      = (ushort*)(ws + ((size_t)32 << 20));  // 32 MB bf16
    int*    edges01 = (int*)  (ws + ((size_t)64 << 20));   // (E0+E1)*4 ~ 4.25 MB
    int*    cnt01   = (int*)  (ws + ((size_t)70 << 20));   // 69632 ints (also cursor)
    int*    tot01   = cnt01 + NC;                           // 272 ints
    int*    offs01  = (int*)  (ws + ((size_t)71 << 20));   // 69633 ints
    ushort* WT0     = (ushort*)(ws + ((size_t)72 << 20));  // 256 KB
    ushort* WT1     = (ushort*)(ws + ((size_t)73 << 20));  // 128 KB
    ushort* mean1   = (ushort*)(ws + ((size_t)74 << 20));  // 2 MB

    // -------- CSR build (both layers fused) --------
    hipMemsetAsync(cnt01, 0, (size_t)(NC + 272) * 4, stream);
    build_wt01<<<768, 256, 0, stream>>>(W_self0, W_neigh0, W_self1, W_neigh1, WT0, WT1);
    edge_hist01<<<(E0 + E1 + 255) / 256, 256, 0, stream>>>(dst0, dst1, cnt01, E0, E1);
    scan_block<<<NC / 256, 256, 0, stream>>>(cnt01, offs01, tot01);
    scan_totals<<<1, 512, 0, stream>>>(tot01, NC / 256);
    scan_add<<<NC / 256, 256, 0, stream>>>(offs01, tot01, cnt01, NC, E0 + E1);
    edge_scatter01<<<(E0 + E1 + 255) / 256, 256, 0, stream>>>(
        src0, dst0, src1, dst1, input_nodes, cnt01, edges01, E0, E1);

    // ================= layer 0 =================
    sage_gather_mean<true><<<N1 / 4, 256, 0, stream>>>(
        embed, offs01, edges01, mean0, N1);
    sage_gemm_mfma<256, true, true, true, true><<<N1 / 64, 256, 0, stream>>>(
        embed, input_nodes, mean0, WT0, b0, h1);

    // ================= layer 1 =================
    sage_gather_mean<false><<<N2 / 4, 256, 0, stream>>>(
        h1, offs01 + N1, edges01, mean1, N2);
    sage_gemm_mfma<128, false, false, false, false><<<N2 / 64, 256, 0, stream>>>(
        h1, nullptr, mean1, WT1, b1, out);
}